// Round 3
// baseline (58386.072 us; speedup 1.0000x reference)
//
#include <hip/hip_runtime.h>
#include <hip/hip_bf16.h>

#define DEV static __device__ __forceinline__

// Problem constants
constexpr int Tn   = 1024;

// Scratch float offsets in static __device__ array (1.17 MB, rewritten
// every launch before any read — no cross-call state).
constexpr int OFF_H      = 0;        // 384*384 = 147456
constexpr int OFF_E      = 147456;   // 16384
constexpr int OFF_EINV   = 163840;   // 16384
constexpr int OFF_M      = 180224;   // 1024
constexpr int OFF_MINV   = 181248;   // 1024
constexpr int OFF_LAM    = 182272;   // 128
constexpr int OFF_SA     = 182400;   // 4096  SA[i][l] = D11[l][i], i<64
constexpr int OFF_SB     = 186496;   // 8192  SB[i][l] = D11[l+64][i]
constexpr int OFF_C1T    = 194688;   // 16384 float2[128][64]
constexpr int OFF_FHT    = 211072;   // 16384 float2[128][64]
constexpr int OFF_B1HT   = 227456;   // 16384 float2[128][64]
constexpr int OFF_B2HT   = 243840;   // 4096  float2[32][64]
constexpr int OFF_D12T   = 247936;   // 4096  float2[32][64]
constexpr int OFF_W0     = 252032;   // 4096  float2[32][64]
constexpr int OFF_Y1     = 256128;   // 8192  [128][64]: cols 0-31 C2T, 32-63 D21T
constexpr int OFF_D22T   = 264320;   // 1024  [32][32]
constexpr int OFF_AUG    = 265344;   // 32768 (128x256 GJ scratch)
constexpr int OFF_AUG2   = 298112;   // 2048  (32x64 GJ scratch)
constexpr int WS_FLOATS  = 300160;

__device__ float g_ws[WS_FLOATS];
__device__ int   g_isf32;

// Dtype-flexible load: f==1 -> buffer is float32, else bf16.
DEV float ld(const void* p, int i, int f) {
  return f ? ((const float*)p)[i]
           : __bfloat162float(((const __hip_bfloat16*)p)[i]);
}
DEV float bcast(float v, int l) {
  return __int_as_float(__builtin_amdgcn_readlane(__float_as_int(v), l));
}

// ---------------- Prep 0: detect input dtype ----------------
// If the buffer is really fp32, bf16-interpreting it yields random exponent
// fields in the low halves -> some |v| >> 1e6 (P(all sane) ~ 1e-61).
// If really bf16 (values ~N(0,0.5)), all |v| < 6.
__global__ void k_detect(const void* __restrict__ X) {
  if (threadIdx.x == 0) {
    const __hip_bfloat16* p = (const __hip_bfloat16*)X;
    int bad = 0;
    for (int i = 0; i < 512; ++i) {
      float v = __bfloat162float(p[i]);
      if (!(v > -1e6f && v < 1e6f)) bad++;   // NaN counts as bad
    }
    g_isf32 = (bad > 0) ? 1 : 0;
  }
}

// ---------------- Prep 1: H = X^T X + eps I (384x384) ----------------
__global__ void k_H(const void* __restrict__ X) {
  const int f = g_isf32;
  float* ws = g_ws;
  int id = blockIdx.x * 256 + threadIdx.x;           // exactly 147456 threads
  int r = id / 384, c = id % 384;
  float acc = 0.f;
  for (int k = 0; k < 384; ++k)
    acc = fmaf(ld(X, k * 384 + r, f), ld(X, k * 384 + c, f), acc);
  if (r == c) acc += 0.001f;
  ws[OFF_H + id] = acc;
}

// ---------------- Prep 2: derived matrices ----------------
__global__ void k_derived(const void* __restrict__ Y,
                          const void* __restrict__ C2,
                          const void* __restrict__ D21,
                          const void* __restrict__ D22,
                          const void* __restrict__ D12) {
  const int f = g_isf32;
  float* ws = g_ws;
  const float* H = ws + OFF_H;
  int id = blockIdx.x * 256 + threadIdx.x;
  if (id < 16384) {                                   // E
    int i = id >> 7, j = id & 127;
    ws[OFF_E + id] = 0.5f * (H[i * 384 + j] + H[(256 + i) * 384 + 256 + j]
                             + ld(Y, i * 128 + j, f) - ld(Y, j * 128 + i, f));
  } else if (id < 24576) {                            // C1T paired: C1 = -H21
    int t = id - 16384; int j = t >> 6, l = t & 63;
    float2 v = make_float2(-H[(128 + l) * 384 + j], -H[(128 + l + 64) * 384 + j]);
    ((float2*)(ws + OFF_C1T))[t] = v;
  } else if (id < 28672) {                            // SA[i][l] = D11[l][i] (i<64)
    int t = id - 24576; int i = t >> 6, l = t & 63;
    ws[OFF_SA + t] = (i < l) ? -H[(128 + l) * 384 + 128 + i] : 0.f;
  } else if (id < 36864) {                            // SB[i][l] = D11[l+64][i]
    int t = id - 28672; int i = t >> 6, l = t & 63; int L = l + 64;
    ws[OFF_SB + t] = (i < L) ? -H[(128 + L) * 384 + 128 + i] : 0.f;
  } else if (id < 36992) {                            // LamInv = 2 / diag(H22) = 1/lam
    int i = id - 36864;
    ws[OFF_LAM + i] = 2.f / H[(128 + i) * 384 + 128 + i];
  } else if (id < 38016) {                            // M = C2 C2^T
    int t = id - 36992; int a = t >> 5, b = t & 31;
    float acc = 0.f;
    for (int j = 0; j < 128; ++j)
      acc = fmaf(ld(C2, a * 128 + j, f), ld(C2, b * 128 + j, f), acc);
    ws[OFF_M + t] = acc;
  } else if (id < 40064) {                            // D12T paired
    int t = id - 38016; int k = t >> 6, l = t & 63;
    ((float2*)(ws + OFF_D12T))[t] =
        make_float2(ld(D12, l * 32 + k, f), ld(D12, (l + 64) * 32 + k, f));
  } else if (id < 48256) {                            // Y1: C2T | D21T
    int t = id - 40064; int j = t >> 6, l = t & 63;
    ws[OFF_Y1 + t] = (l < 32) ? ld(C2, l * 128 + j, f)
                              : ld(D21, (l - 32) * 128 + j, f);
  } else if (id < 49280) {                            // D22T[k][ko] = D22[ko][k]
    int t = id - 48256; int k = t >> 5, ko = t & 31;
    ws[OFF_D22T + t] = ld(D22, ko * 32 + k, f);
  }
}

// ---------------- Prep 3: invert E (128) and M (32), Gauss-Jordan ----------------
// E's symmetric part is PD (diag ~96), so unpivoted GJ is safe.
__global__ void k_inv() {
  float* ws = g_ws;
  __shared__ float col[128];
  float* aug = ws + OFF_AUG;
  const float* E = ws + OFF_E;
  int tid = threadIdx.x;
  for (int idx = tid; idx < 32768; idx += 1024) {
    int i = idx >> 8, j = idx & 255;
    aug[idx] = (j < 128) ? E[i * 128 + j] : ((j - 128) == i ? 1.f : 0.f);
  }
  __syncthreads();
  for (int k = 0; k < 128; ++k) {
    if (tid < 128) col[tid] = aug[tid * 256 + k];
    __syncthreads();
    float d = 1.f / col[k];
    if (tid < 256) aug[k * 256 + tid] *= d;
    __syncthreads();
    int j = tid & 255, iseg = tid >> 8;               // 4 segments x 32 rows
    float rkj = aug[k * 256 + j];
    for (int i = iseg * 32; i < iseg * 32 + 32; ++i) {
      if (i == k) continue;
      aug[i * 256 + j] -= col[i] * rkj;
    }
    __syncthreads();
  }
  for (int idx = tid; idx < 16384; idx += 1024) {
    int i = idx >> 7, j = idx & 127;
    ws[OFF_EINV + idx] = aug[i * 256 + 128 + j];
  }
  __syncthreads();
  // M (32x32)
  float* aug2 = ws + OFF_AUG2;
  const float* M = ws + OFF_M;
  for (int idx = tid; idx < 2048; idx += 1024) {
    int i = idx >> 6, j = idx & 63;
    aug2[idx] = (j < 32) ? M[i * 32 + j] : ((j - 32) == i ? 1.f : 0.f);
  }
  __syncthreads();
  for (int k = 0; k < 32; ++k) {
    if (tid < 32) col[tid] = aug2[tid * 64 + k];
    __syncthreads();
    float d = 1.f / col[k];
    if (tid < 64) aug2[k * 64 + tid] *= d;
    __syncthreads();
    if (tid < 64) {
      float rkj = aug2[k * 64 + tid];
      for (int i = 0; i < 32; ++i) if (i != k) aug2[i * 64 + tid] -= col[i] * rkj;
    }
    __syncthreads();
  }
  for (int idx = tid; idx < 1024; idx += 1024) {
    int i = idx >> 5, j = idx & 31;
    ws[OFF_MINV + idx] = aug2[i * 64 + 32 + j];
  }
}

// ---------------- Prep 4: fused matrices ----------------
__global__ void k_fuse(const void* __restrict__ B2,
                       const void* __restrict__ C2) {
  const int f = g_isf32;
  float* ws = g_ws;
  int id = blockIdx.x * 256 + threadIdx.x;            // 20480 exactly
  const float* einv = ws + OFF_EINV;
  const float* H = ws + OFF_H;
  const float* minv = ws + OFF_MINV;
  if (id < 8192) {                                    // FhT: Fh = Einv @ H31
    int l = id >> 7, j = id & 127;
    float ax = 0.f, ay = 0.f;
    for (int k = 0; k < 128; ++k) {
      float h = H[(256 + k) * 384 + j];
      ax = fmaf(einv[l * 128 + k], h, ax);
      ay = fmaf(einv[(l + 64) * 128 + k], h, ay);
    }
    ((float2*)(ws + OFF_FHT))[j * 64 + l] = make_float2(ax, ay);
  } else if (id < 16384) {                            // B1hT: B1h = Einv @ H32
    int t = id - 8192; int l = t >> 7, j = t & 127;
    float ax = 0.f, ay = 0.f;
    for (int k = 0; k < 128; ++k) {
      float h = H[(256 + k) * 384 + 128 + j];
      ax = fmaf(einv[l * 128 + k], h, ax);
      ay = fmaf(einv[(l + 64) * 128 + k], h, ay);
    }
    ((float2*)(ws + OFF_B1HT))[j * 64 + l] = make_float2(ax, ay);
  } else if (id < 18432) {                            // B2hT: B2h = Einv @ B2
    int t = id - 16384; int l = t >> 5, ki = t & 31;
    float ax = 0.f, ay = 0.f;
    for (int k = 0; k < 128; ++k) {
      float bv = ld(B2, k * 32 + ki, f);
      ax = fmaf(einv[l * 128 + k], bv, ax);
      ay = fmaf(einv[(l + 64) * 128 + k], bv, ay);
    }
    ((float2*)(ws + OFF_B2HT))[ki * 64 + l] = make_float2(ax, ay);
  } else if (id < 20480) {                            // W0 = Minv @ C2
    int t = id - 18432; int k = t >> 6, l = t & 63;
    float ax = 0.f, ay = 0.f;
    for (int m = 0; m < 32; ++m) {
      float mv = minv[k * 32 + m];
      ax = fmaf(mv, ld(C2, m * 128 + l, f), ax);
      ay = fmaf(mv, ld(C2, m * 128 + l + 64, f), ay);
    }
    ((float2*)(ws + OFF_W0))[k * 64 + l] = make_float2(ax, ay);
  }
}

// ---------------- Main recurrent kernel: one wave per batch row ----------------
__global__ __launch_bounds__(512) void k_ren(const void* __restrict__ x0s,
                                             const void* __restrict__ u_in,
                                             void* __restrict__ out) {
  const int f = g_isf32;
  const float* ws = g_ws;
  __shared__ float sSA[64 * 64];    // 16 KB
  __shared__ float sSB[128 * 64];   // 32 KB
  for (int idx = threadIdx.x; idx < 4096; idx += 512) sSA[idx] = ws[OFF_SA + idx];
  for (int idx = threadIdx.x; idx < 8192; idx += 512) sSB[idx] = ws[OFF_SB + idx];
  __syncthreads();

  const int lane = threadIdx.x & 63;
  const int wave = threadIdx.x >> 6;
  const int b = blockIdx.x * 8 + wave;

  const float2* C1T  = (const float2*)(ws + OFF_C1T);
  const float2* FHT  = (const float2*)(ws + OFF_FHT);
  const float2* B1HT = (const float2*)(ws + OFF_B1HT);
  const float2* B2HT = (const float2*)(ws + OFF_B2HT);
  const float2* D12T = (const float2*)(ws + OFF_D12T);
  const float2* W0   = (const float2*)(ws + OFF_W0);
  const float* Y1    = ws + OFF_Y1;
  const float* D22T  = ws + OFF_D22T;

  const float l2_lo = 2.f * ws[OFF_LAM + lane];        // 2/lam
  const float l2_hi = 2.f * ws[OFF_LAM + 64 + lane];

  // x0 = (y0_sys @ Minv) @ C2 = y0_sys @ W0
  float yv = (lane < 32) ? ld(x0s, b * 32 + lane, f) : 0.f;
  float x_lo = 0.f, x_hi = 0.f;
#pragma unroll 8
  for (int k = 0; k < 32; ++k) {
    float yk = bcast(yv, k);
    float2 wv = W0[k * 64 + lane];
    x_lo = fmaf(wv.x, yk, x_lo);
    x_hi = fmaf(wv.y, yk, x_hi);
  }
  float w_lo = 0.f, w_hi = 0.f, uv = 0.f;

  auto emit = [&](int tout) {
    float part = 0.f;
#pragma unroll 8
    for (int j = 0; j < 64; ++j) {
      float av = bcast(x_lo, j), bv = bcast(w_lo, j);
      float m = (lane < 32) ? av : bv;
      part = fmaf(Y1[j * 64 + lane], m, part);
    }
#pragma unroll 8
    for (int j = 0; j < 64; ++j) {
      float av = bcast(x_hi, j), bv = bcast(w_hi, j);
      float m = (lane < 32) ? av : bv;
      part = fmaf(Y1[(j + 64) * 64 + lane], m, part);
    }
#pragma unroll 8
    for (int k = 0; k < 32; ++k) {
      float uk = bcast(uv, k);
      float dv = (lane < 32) ? D22T[k * 32 + lane] : 0.f;
      part = fmaf(dv, uk, part);
    }
    part += __shfl_down(part, 32);
    if (lane < 32) {
      size_t oi = ((size_t)b * Tn + tout) * 32 + lane;
      if (f) ((float*)out)[oi] = part;
      else   ((__hip_bfloat16*)out)[oi] = __float2bfloat16(part);
    }
  };

  emit(0);  // y0 = x0 @ C2^T   (w = u = 0)

#pragma unroll 1
  for (int t = 0; t < Tn - 1; ++t) {
    uv = (lane < 32) ? ld(u_in, ((size_t)b * Tn + t) * 32 + lane, f) : 0.f;

    // a = x @ C1^T + u @ D12^T
    float acc_lo = 0.f, acc_hi = 0.f;
#pragma unroll 8
    for (int j = 0; j < 64; ++j) {
      float xj = bcast(x_lo, j);
      float2 cv = C1T[j * 64 + lane];
      acc_lo = fmaf(cv.x, xj, acc_lo);
      acc_hi = fmaf(cv.y, xj, acc_hi);
    }
#pragma unroll 8
    for (int j = 0; j < 64; ++j) {
      float xj = bcast(x_hi, j);
      float2 cv = C1T[(j + 64) * 64 + lane];
      acc_lo = fmaf(cv.x, xj, acc_lo);
      acc_hi = fmaf(cv.y, xj, acc_hi);
    }
#pragma unroll 8
    for (int k = 0; k < 32; ++k) {
      float uk = bcast(uv, k);
      float2 dv = D12T[k * 64 + lane];
      acc_lo = fmaf(dv.x, uk, acc_lo);
      acc_hi = fmaf(dv.y, uk, acc_hi);
    }

    // sequential tanh forward substitution: w_i = tanh(2*acc_i/lam_i scaled)
    w_lo = 0.f; w_hi = 0.f;
#pragma unroll
    for (int i = 0; i < 64; ++i) {
      float r = bcast(acc_lo * l2_lo, i);          // r = 2 v_i / lam_i
      float e = __expf(r);
      float wi = 1.f - 2.f * __builtin_amdgcn_rcpf(1.f + e);
      acc_lo = fmaf(sSA[i * 64 + lane], wi, acc_lo);
      acc_hi = fmaf(sSB[i * 64 + lane], wi, acc_hi);
      w_lo = (lane == i) ? wi : w_lo;
    }
#pragma unroll
    for (int i = 0; i < 64; ++i) {
      float r = bcast(acc_hi * l2_hi, i);
      float e = __expf(r);
      float wi = 1.f - 2.f * __builtin_amdgcn_rcpf(1.f + e);
      acc_hi = fmaf(sSB[(i + 64) * 64 + lane], wi, acc_hi);
      w_hi = (lane == i) ? wi : w_hi;
    }

    // x_new = x @ Fh^T + w @ B1h^T + u @ B2h^T   (E^{-1} pre-fused)
    float xn_lo = 0.f, xn_hi = 0.f;
#pragma unroll 8
    for (int j = 0; j < 64; ++j) {
      float xj = bcast(x_lo, j), wj = bcast(w_lo, j);
      float2 fv = FHT[j * 64 + lane], g = B1HT[j * 64 + lane];
      xn_lo = fmaf(fv.x, xj, fmaf(g.x, wj, xn_lo));
      xn_hi = fmaf(fv.y, xj, fmaf(g.y, wj, xn_hi));
    }
#pragma unroll 8
    for (int j = 0; j < 64; ++j) {
      float xj = bcast(x_hi, j), wj = bcast(w_hi, j);
      float2 fv = FHT[(j + 64) * 64 + lane], g = B1HT[(j + 64) * 64 + lane];
      xn_lo = fmaf(fv.x, xj, fmaf(g.x, wj, xn_lo));
      xn_hi = fmaf(fv.y, xj, fmaf(g.y, wj, xn_hi));
    }
#pragma unroll 8
    for (int k = 0; k < 32; ++k) {
      float uk = bcast(uv, k);
      float2 bv = B2HT[k * 64 + lane];
      xn_lo = fmaf(bv.x, uk, xn_lo);
      xn_hi = fmaf(bv.y, uk, xn_hi);
    }
    x_lo = xn_lo; x_hi = xn_hi;

    emit(t + 1);  // y_t lands at output index t+1
  }
}

extern "C" void kernel_launch(void* const* d_in, const int* in_sizes, int n_in,
                              void* d_out, int out_size, void* d_ws, size_t ws_size,
                              hipStream_t stream) {
  const void* x0s = d_in[0];
  const void* u   = d_in[1];
  const void* X   = d_in[2];
  const void* Y   = d_in[3];
  const void* B2  = d_in[4];
  const void* C2  = d_in[5];
  const void* D21 = d_in[6];
  const void* D22 = d_in[7];
  const void* D12 = d_in[8];
  (void)d_ws; (void)ws_size; (void)in_sizes; (void)n_in; (void)out_size;

  hipLaunchKernelGGL(k_detect,  dim3(1),   dim3(64),  0, stream, X);
  hipLaunchKernelGGL(k_H,       dim3(576), dim3(256), 0, stream, X);
  hipLaunchKernelGGL(k_derived, dim3(193), dim3(256), 0, stream, Y, C2, D21, D22, D12);
  hipLaunchKernelGGL(k_inv,     dim3(1),   dim3(1024), 0, stream);
  hipLaunchKernelGGL(k_fuse,    dim3(80),  dim3(256), 0, stream, B2, C2);
  hipLaunchKernelGGL(k_ren,     dim3(32),  dim3(512), 0, stream, x0s, u, d_out);
}

// Round 6
// 8547.531 us; speedup vs baseline: 6.8308x; 6.8308x over previous
//
#include <hip/hip_runtime.h>
#include <hip/hip_bf16.h>

#define DEV static __device__ __forceinline__

constexpr int Tn = 1024;
constexpr float LOG2E = 1.4426950408889634f;

// ---- g_ws float offsets ----
constexpr int OFF_H     = 0;        // 384*384
constexpr int OFF_E     = 147456;   // 16384
constexpr int OFF_EINV  = 163840;   // 16384
constexpr int OFF_M     = 180224;   // 1024
constexpr int OFF_MINV  = 181248;   // 1024
constexpr int OFF_GL2   = 182272;   // 128: (4/diag(H22))*log2(e) = (2/lam)*log2e
constexpr int OFF_FH    = 182400;   // 16384  Fh[l][j] = (Einv H31)
constexpr int OFF_B1H   = 198784;   // 16384  B1h[l][j] = (Einv H32)
constexpr int OFF_B2H   = 215168;   // 4096   B2h[l][k] = (Einv B2)
constexpr int OFF_W0    = 219264;   // 4096   W0[k][l] = (Minv C2)
constexpr int OFF_WC    = 223360;   // 4096   WC[k][l] = sum_m W0[k][m] C1[l][m]
constexpr int OFF_PF    = 227456;   // 16384 (8192 f2) PF[j][l]=(Fh[l][j],Fh[l+64][j])
constexpr int OFF_PB    = 243840;   // 16384 (8192 f2) B1h pairs
constexpr int OFF_PC    = 260224;   // 16384 (8192 f2) gl2-scaled C1 pairs
constexpr int OFF_SAB   = 276608;   // 8192  (4096 f2) scan couplings lower half
constexpr int OFF_SB2   = 284800;   // 4096            scan couplings upper half
constexpr int OFF_BUQ   = 288896;   // 4096 (2048 f2) BUq[k][l]=(B2h[l][k],B2h[l+64][k])
constexpr int OFF_D12Q  = 292992;   // 4096 (2048 f2) gl2-scaled D12 pairs
constexpr int OFF_WCS   = 297088;   // 4096 (2048 f2) gl2-scaled WC pairs
constexpr int OFF_C2Y   = 301184;   // 4096  C2Y[m][o] = C2[o][m]
constexpr int OFF_D21Y  = 305280;   // 4096  D21Y[m][o] = D21[o][m]
constexpr int OFF_D22Y  = 309376;   // 1024  D22Y[k][o] = D22[o][k]
constexpr int OFF_AUG   = 310400;   // 32768
constexpr int OFF_AUG2  = 343168;   // 2048
constexpr int OFF_X0    = 345216;   // 32768: x0[b][l] plain
constexpr int OFF_A0    = 377984;   // 32768: a0[b][lane] f2 (gl2-scaled, exp2 units)
constexpr int WS_FLOATS = 410752;

__device__ __align__(16) float g_ws[WS_FLOATS];
__device__ int g_isf32;
// trajectory streams (fully rewritten before read, every launch)
__device__ float4 g_Q [256 * 1024 * 64];   // (bu_lo,bu_hi,du_lo,du_hi) per (b,t,lane)
__device__ float2 g_Xs[256 * 1024 * 64];   // x_t components (l, l+64)
__device__ float2 g_Ws[256 * 1024 * 64];   // w_t components (l, l+64)

DEV float ld(const void* p, int i, int f) {
  return f ? ((const float*)p)[i]
           : __bfloat162float(((const __hip_bfloat16*)p)[i]);
}
DEV float rdlane(float v, int l) {
  return __int_as_float(__builtin_amdgcn_readlane(__float_as_int(v), l));
}

// ---------------- Prep 0: detect input dtype ----------------
__global__ void k_detect(const void* __restrict__ X) {
  if (threadIdx.x == 0) {
    const __hip_bfloat16* p = (const __hip_bfloat16*)X;
    int bad = 0;
    for (int i = 0; i < 512; ++i) {
      float v = __bfloat162float(p[i]);
      if (!(v > -1e6f && v < 1e6f)) bad++;
    }
    g_isf32 = (bad > 0) ? 1 : 0;
  }
}

// ---------------- Prep 1: H = X^T X + eps I ----------------
__global__ void k_H(const void* __restrict__ X) {
  const int f = g_isf32;
  float* ws = g_ws;
  int id = blockIdx.x * 256 + threadIdx.x;   // 147456
  int r = id / 384, c = id % 384;
  float acc = 0.f;
  for (int k = 0; k < 384; ++k)
    acc = fmaf(ld(X, k * 384 + r, f), ld(X, k * 384 + c, f), acc);
  if (r == c) acc += 0.001f;
  ws[OFF_H + id] = acc;
}

// ---------------- Prep 2: E, gl2, M ----------------
__global__ void k_derived(const void* __restrict__ Y, const void* __restrict__ C2) {
  const int f = g_isf32;
  float* ws = g_ws;
  const float* H = ws + OFF_H;
  int id = blockIdx.x * 256 + threadIdx.x;
  if (id < 16384) {
    int i = id >> 7, j = id & 127;
    ws[OFF_E + id] = 0.5f * (H[i * 384 + j] + H[(256 + i) * 384 + 256 + j]
                             + ld(Y, i * 128 + j, f) - ld(Y, j * 128 + i, f));
  } else if (id < 16512) {
    int i = id - 16384;
    ws[OFF_GL2 + i] = LOG2E * 4.f / H[(128 + i) * 384 + 128 + i];  // (2/lam)*log2e
  } else if (id < 17536) {
    int t = id - 16512; int a = t >> 5, b = t & 31;
    float acc = 0.f;
    for (int j = 0; j < 128; ++j)
      acc = fmaf(ld(C2, a * 128 + j, f), ld(C2, b * 128 + j, f), acc);
    ws[OFF_M + t] = acc;
  }
}

// ---------------- Prep 3: invert E (128) and M (32), Gauss-Jordan ----------------
// (round-3-verified structure; E's symmetric part is PD, diag ~96)
__global__ void k_inv() {
  float* ws = g_ws;
  __shared__ float col[128];
  float* aug = ws + OFF_AUG;
  const float* E = ws + OFF_E;
  int tid = threadIdx.x;
  for (int idx = tid; idx < 32768; idx += 1024) {
    int i = idx >> 8, j = idx & 255;
    aug[idx] = (j < 128) ? E[i * 128 + j] : ((j - 128) == i ? 1.f : 0.f);
  }
  __syncthreads();
  for (int k = 0; k < 128; ++k) {
    if (tid < 128) col[tid] = aug[tid * 256 + k];
    __syncthreads();
    float d = 1.f / col[k];
    if (tid < 256) aug[k * 256 + tid] *= d;
    __syncthreads();
    int j = tid & 255, iseg = tid >> 8;
    float rkj = aug[k * 256 + j];
    for (int i = iseg * 32; i < iseg * 32 + 32; ++i) {
      if (i == k) continue;
      aug[i * 256 + j] -= col[i] * rkj;
    }
    __syncthreads();
  }
  for (int idx = tid; idx < 16384; idx += 1024) {
    int i = idx >> 7, j = idx & 127;
    ws[OFF_EINV + idx] = aug[i * 256 + 128 + j];
  }
  __syncthreads();
  float* aug2 = ws + OFF_AUG2;
  const float* M = ws + OFF_M;
  for (int idx = tid; idx < 2048; idx += 1024) {
    int i = idx >> 6, j = idx & 63;
    aug2[idx] = (j < 32) ? M[i * 32 + j] : ((j - 32) == i ? 1.f : 0.f);
  }
  __syncthreads();
  for (int k = 0; k < 32; ++k) {
    if (tid < 32) col[tid] = aug2[tid * 64 + k];
    __syncthreads();
    float d = 1.f / col[k];
    if (tid < 64) aug2[k * 64 + tid] *= d;
    __syncthreads();
    if (tid < 64) {
      float rkj = aug2[k * 64 + tid];
      for (int i = 0; i < 32; ++i) if (i != k) aug2[i * 64 + tid] -= col[i] * rkj;
    }
    __syncthreads();
  }
  for (int idx = tid; idx < 1024; idx += 1024) {
    int i = idx >> 5, j = idx & 31;
    ws[OFF_MINV + idx] = aug2[i * 64 + 32 + j];
  }
}

// ---------------- Prep 4: Fh, B1h, B2h, W0 ----------------
__global__ void k_fuse(const void* __restrict__ B2, const void* __restrict__ C2) {
  const int f = g_isf32;
  float* ws = g_ws;
  const float* einv = ws + OFF_EINV;
  const float* H = ws + OFF_H;
  const float* minv = ws + OFF_MINV;
  int id = blockIdx.x * 256 + threadIdx.x;   // 40960
  if (id < 16384) {                  // Fh[l][j] = Einv @ H31
    int l = id >> 7, j = id & 127;
    float a = 0.f;
    for (int m = 0; m < 128; ++m) a = fmaf(einv[l * 128 + m], H[(256 + m) * 384 + j], a);
    ws[OFF_FH + id] = a;
  } else if (id < 32768) {           // B1h[l][j] = Einv @ H32
    int t = id - 16384; int l = t >> 7, j = t & 127;
    float a = 0.f;
    for (int m = 0; m < 128; ++m) a = fmaf(einv[l * 128 + m], H[(256 + m) * 384 + 128 + j], a);
    ws[OFF_B1H + t] = a;
  } else if (id < 36864) {           // B2h[l][k] = Einv @ B2
    int t = id - 32768; int l = t >> 5, k = t & 31;
    float a = 0.f;
    for (int m = 0; m < 128; ++m) a = fmaf(einv[l * 128 + m], ld(B2, m * 32 + k, f), a);
    ws[OFF_B2H + t] = a;
  } else if (id < 40960) {           // W0[k][l] = Minv @ C2
    int t = id - 36864; int k = t >> 7, l = t & 127;
    float a = 0.f;
    for (int m = 0; m < 32; ++m) a = fmaf(minv[k * 32 + m], ld(C2, m * 128 + l, f), a);
    ws[OFF_W0 + t] = a;
  }
}

// ---------------- Prep 5: WC[k][l] = sum_m W0[k][m]*C1[l][m] ----------------
__global__ void k_w2() {
  float* ws = g_ws;
  const float* H = ws + OFF_H;
  const float* w0 = ws + OFF_W0;
  int id = blockIdx.x * 256 + threadIdx.x;   // 4096
  int k = id >> 7, l = id & 127;
  float a = 0.f;
  for (int m = 0; m < 128; ++m) a = fmaf(w0[k * 128 + m], -H[(128 + l) * 384 + m], a);
  ws[OFF_WC + id] = a;
}

// ---------------- Prep 6: packed/scaled layouts ----------------
__global__ void k_pk(const void* __restrict__ D12, const void* __restrict__ C2,
                     const void* __restrict__ D21, const void* __restrict__ D22) {
  const int f = g_isf32;
  float* ws = g_ws;
  const float* H = ws + OFF_H;
  const float* g = ws + OFF_GL2;
  int id = blockIdx.x * 256 + threadIdx.x;   // 48128
  if (id < 8192) {                   // PF pairs
    int j = id >> 6, l = id & 63;
    ((float2*)(ws + OFF_PF))[id] =
        make_float2(ws[OFF_FH + l * 128 + j], ws[OFF_FH + (l + 64) * 128 + j]);
  } else if (id < 16384) {           // PB pairs
    int t = id - 8192; int j = t >> 6, l = t & 63;
    ((float2*)(ws + OFF_PB))[t] =
        make_float2(ws[OFF_B1H + l * 128 + j], ws[OFF_B1H + (l + 64) * 128 + j]);
  } else if (id < 24576) {           // PC pairs: gl2-scaled C1 = -H21
    int t = id - 16384; int j = t >> 6, l = t & 63;
    ((float2*)(ws + OFF_PC))[t] =
        make_float2(-g[l] * H[(128 + l) * 384 + j], -g[l + 64] * H[(192 + l) * 384 + j]);
  } else if (id < 28672) {           // SAB: scan couplings, w_i (i<64)
    int t = id - 24576; int i = t >> 6, l = t & 63;
    float sx = (i < l) ? -g[l] * H[(128 + l) * 384 + 128 + i] : 0.f;
    float sy = -g[l + 64] * H[(192 + l) * 384 + 128 + i];   // i<64<=l+64 strict
    ((float2*)(ws + OFF_SAB))[t] = make_float2(sx, sy);
  } else if (id < 32768) {           // SB2: w_{i+64} -> rows l+64
    int t = id - 28672; int ii = t >> 6, l = t & 63;
    ws[OFF_SB2 + t] = (ii < l) ? -g[l + 64] * H[(192 + l) * 384 + 192 + ii] : 0.f;
  } else if (id < 34816) {           // BUq pairs
    int t = id - 32768; int k = t >> 6, l = t & 63;
    ((float2*)(ws + OFF_BUQ))[t] =
        make_float2(ws[OFF_B2H + l * 32 + k], ws[OFF_B2H + (l + 64) * 32 + k]);
  } else if (id < 36864) {           // D12Q pairs (gl2-scaled)
    int t = id - 34816; int k = t >> 6, l = t & 63;
    ((float2*)(ws + OFF_D12Q))[t] =
        make_float2(g[l] * ld(D12, l * 32 + k, f), g[l + 64] * ld(D12, (l + 64) * 32 + k, f));
  } else if (id < 38912) {           // WCs pairs (gl2-scaled)
    int t = id - 36864; int k = t >> 6, l = t & 63;
    ((float2*)(ws + OFF_WCS))[t] =
        make_float2(g[l] * ws[OFF_WC + k * 128 + l], g[l + 64] * ws[OFF_WC + k * 128 + l + 64]);
  } else if (id < 43008) {           // C2Y[m][o]
    int t = id - 38912; int m = t >> 5, o = t & 31;
    ws[OFF_C2Y + t] = ld(C2, o * 128 + m, f);
  } else if (id < 47104) {           // D21Y[m][o]
    int t = id - 43008; int m = t >> 5, o = t & 31;
    ws[OFF_D21Y + t] = ld(D21, o * 128 + m, f);
  } else if (id < 48128) {           // D22Y[k][o]
    int t = id - 47104; int k = t >> 5, o = t & 31;
    ws[OFF_D22Y + t] = ld(D22, o * 32 + k, f);
  }
}

// ---------------- Prep 7: x0 and a0 ----------------
__global__ void k_x0a0(const void* __restrict__ x0s, const void* __restrict__ u_in) {
  const int f = g_isf32;
  float* ws = g_ws;
  int id = blockIdx.x * 256 + threadIdx.x;   // 49152
  if (id < 32768) {                  // x0[b][l] = sum_k y0[b][k] W0[k][l]
    int b = id >> 7, l = id & 127;
    float a = 0.f;
    for (int k = 0; k < 32; ++k)
      a = fmaf(ld(x0s, b * 32 + k, f), ws[OFF_W0 + k * 128 + l], a);
    ws[OFF_X0 + id] = a;
  } else {                           // a0[b][lane] f2 = gl2*(C1 x0 + D12 u0)
    int t = id - 32768; int b = t >> 6, lane = t & 63;
    const float2* WCs = (const float2*)(ws + OFF_WCS);
    const float2* D12Q = (const float2*)(ws + OFF_D12Q);
    float ax = 0.f, ay = 0.f;
    for (int k = 0; k < 32; ++k) {
      float yk = ld(x0s, b * 32 + k, f);
      float2 wc = WCs[k * 64 + lane];
      ax = fmaf(wc.x, yk, ax); ay = fmaf(wc.y, yk, ay);
      float u0 = ld(u_in, b * Tn * 32 + k, f);
      float2 dq = D12Q[k * 64 + lane];
      ax = fmaf(dq.x, u0, ax); ay = fmaf(dq.y, u0, ay);
    }
    ((float2*)(ws + OFF_A0))[b * 64 + lane] = make_float2(ax, ay);
  }
}

// ---------------- Prep 8: u-injection stream ----------------
__global__ __launch_bounds__(256) void k_q(const void* __restrict__ u_in) {
  const int f = g_isf32;
  const float* ws = g_ws;
  int lane = threadIdx.x & 63, wave = threadIdx.x >> 6;
  int idx = blockIdx.x * 4 + wave;           // (b,t)
  int b = idx >> 10, t = idx & 1023;
  if (t >= Tn - 1) return;
  const float2* BUq = (const float2*)(ws + OFF_BUQ);
  const float2* D12Q = (const float2*)(ws + OFF_D12Q);
  float bx = 0.f, by = 0.f, dx = 0.f, dy = 0.f;
#pragma unroll 8
  for (int k = 0; k < 32; ++k) {
    float u0 = ld(u_in, (b * Tn + t) * 32 + k, f);
    float2 bu = BUq[k * 64 + lane];
    bx = fmaf(bu.x, u0, bx); by = fmaf(bu.y, u0, by);
    float u1 = ld(u_in, (b * Tn + t + 1) * 32 + k, f);
    float2 dq = D12Q[k * 64 + lane];
    dx = fmaf(dq.x, u1, dx); dy = fmaf(dq.y, u1, dy);
  }
  g_Q[((size_t)b * Tn + t) * 64 + lane] = make_float4(bx, by, dx, dy);
}

// ---------------- Main: 1 row/block, 4 waves; weights in regs+LDS ----------------
__global__ __launch_bounds__(256, 1) void k_scanx() {
  __shared__ float2 sSAB[64 * 64];   // 32 KB
  __shared__ float  sSB2[64 * 64];   // 16 KB
  __shared__ float2 xbuf[4][64];     // 2 KB
  __shared__ float2 abuf[4][64];     // 2 KB
  const float* ws = g_ws;
  const int tid = threadIdx.x, lane = tid & 63, w = tid >> 6;
  for (int i = tid; i < 4096; i += 256) sSAB[i] = ((const float2*)(ws + OFF_SAB))[i];
  for (int i = tid; i < 4096; i += 256) sSB2[i] = ws[OFF_SB2 + i];

  // per-wave register matrices: columns [32w, 32w+32)
  float2 vFh[32], vB1[32], vC1[32];
  const float2* PF = (const float2*)(ws + OFF_PF);
  const float2* PB = (const float2*)(ws + OFF_PB);
  const float2* PC = (const float2*)(ws + OFF_PC);
#pragma unroll
  for (int c = 0; c < 32; ++c) {
    vFh[c] = PF[(32 * w + c) * 64 + lane];
    vB1[c] = PB[(32 * w + c) * 64 + lane];
    vC1[c] = PC[(32 * w + c) * 64 + lane];
  }
  const int b = blockIdx.x;
  // xq: lane l holds x-component 32w + (l&31) (dup in upper halves)
  float xq = ws[OFF_X0 + b * 128 + 32 * w + (lane & 31)];
  float2 a2 = ((const float2*)(ws + OFF_A0))[b * 64 + lane];
  float accx = a2.x, accy = a2.y;
  const float4* Q = g_Q + (size_t)b * Tn * 64;
  float4 q = Q[lane];
  size_t sbase = (size_t)b * Tn * 64 + lane;
  const int idx0 = 32 * (w & 1);
  __syncthreads();

#pragma unroll 1
  for (int t = 0; t < Tn - 1; ++t) {
    float4 qn = q;
    if (t + 1 < Tn - 1) qn = Q[(size_t)(t + 1) * 64 + lane];

    // --- serial tanh scan (redundant on all 4 waves; exp2 units) ---
    float wx = 0.f, wy = 0.f;
#pragma unroll
    for (int i = 0; i < 64; ++i) {
      float s = rdlane(accx, i);
      float e2 = __builtin_amdgcn_exp2f(s);
      float wi = fmaf(-2.f, __builtin_amdgcn_rcpf(1.f + e2), 1.f);
      float2 sp = sSAB[i * 64 + lane];
      accx = fmaf(sp.x, wi, accx);
      accy = fmaf(sp.y, wi, accy);
      wx = (lane == i) ? wi : wx;
    }
#pragma unroll
    for (int i = 0; i < 64; ++i) {
      float s = rdlane(accy, i);
      float e2 = __builtin_amdgcn_exp2f(s);
      float wi = fmaf(-2.f, __builtin_amdgcn_rcpf(1.f + e2), 1.f);
      accy = fmaf(sSB2[i * 64 + lane], wi, accy);
      wy = (lane == i) ? wi : wy;
    }
    if (w == 0) g_Ws[sbase + (size_t)t * 64] = make_float2(wx, wy);

    // --- x' partial: Fh cols (x_t) + B1h cols (w_t) + bu (wave 0) ---
    float px = (w == 0) ? q.x : 0.f, py = (w == 0) ? q.y : 0.f;
#pragma unroll
    for (int c = 0; c < 32; ++c) {
      float xj = rdlane(xq, c);
      px = fmaf(vFh[c].x, xj, px);
      py = fmaf(vFh[c].y, xj, py);
    }
    if (w < 2) {
#pragma unroll
      for (int c = 0; c < 32; ++c) {
        float wv = rdlane(wx, idx0 + c);
        px = fmaf(vB1[c].x, wv, px);
        py = fmaf(vB1[c].y, wv, py);
      }
    } else {
#pragma unroll
      for (int c = 0; c < 32; ++c) {
        float wv = rdlane(wy, idx0 + c);
        px = fmaf(vB1[c].x, wv, px);
        py = fmaf(vB1[c].y, wv, py);
      }
    }
    xbuf[w][lane] = make_float2(px, py);
    __syncthreads();

    // --- assemble x_{t+1}: quarter view (xq) + full store (wave 3) ---
    {
      int m = idx0 + (lane & 31);
      float2 s0 = xbuf[0][m], s1 = xbuf[1][m], s2 = xbuf[2][m], s3 = xbuf[3][m];
      float xl = s0.x + s1.x + s2.x + s3.x;
      float xh = s0.y + s1.y + s2.y + s3.y;
      xq = (w < 2) ? xl : xh;
      if (w == 3) {
        float2 f0 = xbuf[0][lane], f1 = xbuf[1][lane], f2v = xbuf[2][lane], f3 = xbuf[3][lane];
        g_Xs[sbase + (size_t)(t + 1) * 64] =
            make_float2(f0.x + f1.x + f2v.x + f3.x, f0.y + f1.y + f2v.y + f3.y);
      }
    }

    // --- a' partial: gl2-scaled C1 cols (x_{t+1}) + du (wave 0) ---
    float pax = (w == 0) ? q.z : 0.f, pay = (w == 0) ? q.w : 0.f;
#pragma unroll
    for (int c = 0; c < 32; ++c) {
      float xj = rdlane(xq, c);
      pax = fmaf(vC1[c].x, xj, pax);
      pay = fmaf(vC1[c].y, xj, pay);
    }
    abuf[w][lane] = make_float2(pax, pay);
    __syncthreads();
    {
      float2 a0v = abuf[0][lane], a1v = abuf[1][lane], a2v = abuf[2][lane], a3v = abuf[3][lane];
      accx = a0v.x + a1v.x + a2v.x + a3v.x;
      accy = a0v.y + a1v.y + a2v.y + a3v.y;
    }
    q = qn;
  }
}

// ---------------- Output GEMM: y_tau = C2 x_tau + D21 w_{tau-1} + D22 u_{tau-1} ----------------
__global__ __launch_bounds__(256) void k_y(const void* __restrict__ x0s,
                                           const void* __restrict__ u_in,
                                           void* __restrict__ out) {
  const int f = g_isf32;
  const float* ws = g_ws;
  int lane = threadIdx.x & 63, wave = threadIdx.x >> 6;
  int idx = blockIdx.x * 4 + wave;
  int b = idx >> 10, tau = idx & 1023;
  int o = lane & 31, h = lane >> 5;
  if (tau == 0) {                    // y0 = y0_sys exactly (C2 pinv(C2) = I)
    if (lane < 32) {
      size_t oi = (size_t)b * Tn * 32 + o;
      float v = ld(x0s, b * 32 + o, f);
      if (f) ((float*)out)[oi] = v;
      else   ((__hip_bfloat16*)out)[oi] = __float2bfloat16(v);
    }
    return;
  }
  const float* Xf = (const float*)g_Xs;
  const float* Wf = (const float*)g_Ws;
  const float* C2Y = ws + OFF_C2Y;
  const float* D21Y = ws + OFF_D21Y;
  const float* D22Y = ws + OFF_D22Y;
  size_t rbase = ((size_t)b * Tn + tau) * 128;
  size_t pbase = ((size_t)b * Tn + tau - 1) * 128;
  float acc = 0.f;
#pragma unroll 8
  for (int l = 0; l < 64; ++l)
    acc = fmaf(Xf[rbase + 2 * l + h], C2Y[(l + 64 * h) * 32 + o], acc);
#pragma unroll 8
  for (int l = 0; l < 64; ++l)
    acc = fmaf(Wf[pbase + 2 * l + h], D21Y[(l + 64 * h) * 32 + o], acc);
  if (h == 0) {                      // u-part once (guarded!)
#pragma unroll 8
    for (int k = 0; k < 32; ++k)
      acc = fmaf(ld(u_in, (b * Tn + tau - 1) * 32 + k, f), D22Y[k * 32 + o], acc);
  }
  acc += __shfl_down(acc, 32);
  if (lane < 32) {
    size_t oi = ((size_t)b * Tn + tau) * 32 + o;
    if (f) ((float*)out)[oi] = acc;
    else   ((__hip_bfloat16*)out)[oi] = __float2bfloat16(acc);
  }
}

extern "C" void kernel_launch(void* const* d_in, const int* in_sizes, int n_in,
                              void* d_out, int out_size, void* d_ws, size_t ws_size,
                              hipStream_t stream) {
  const void* x0s = d_in[0];
  const void* u   = d_in[1];
  const void* X   = d_in[2];
  const void* Y   = d_in[3];
  const void* B2  = d_in[4];
  const void* C2  = d_in[5];
  const void* D21 = d_in[6];
  const void* D22 = d_in[7];
  const void* D12 = d_in[8];
  (void)d_ws; (void)ws_size; (void)in_sizes; (void)n_in; (void)out_size;

  hipLaunchKernelGGL(k_detect,  dim3(1),     dim3(64),   0, stream, X);
  hipLaunchKernelGGL(k_H,       dim3(576),   dim3(256),  0, stream, X);
  hipLaunchKernelGGL(k_derived, dim3(69),    dim3(256),  0, stream, Y, C2);
  hipLaunchKernelGGL(k_inv,     dim3(1),     dim3(1024), 0, stream);
  hipLaunchKernelGGL(k_fuse,    dim3(160),   dim3(256),  0, stream, B2, C2);
  hipLaunchKernelGGL(k_w2,      dim3(16),    dim3(256),  0, stream);
  hipLaunchKernelGGL(k_pk,      dim3(188),   dim3(256),  0, stream, D12, C2, D21, D22);
  hipLaunchKernelGGL(k_x0a0,    dim3(192),   dim3(256),  0, stream, x0s, u);
  hipLaunchKernelGGL(k_q,       dim3(65536), dim3(256),  0, stream, u);
  hipLaunchKernelGGL(k_scanx,   dim3(256),   dim3(256),  0, stream);
  hipLaunchKernelGGL(k_y,       dim3(65536), dim3(256),  0, stream, x0s, u, d_out);
}

// Round 7
// 8004.184 us; speedup vs baseline: 7.2944x; 1.0679x over previous
//
#include <hip/hip_runtime.h>
#include <hip/hip_bf16.h>

#define DEV static __device__ __forceinline__

constexpr int Tn = 1024;
constexpr float LOG2E = 1.4426950408889634f;

// ---- g_ws float offsets ----
constexpr int OFF_H     = 0;        // 384*384
constexpr int OFF_E     = 147456;   // 16384
constexpr int OFF_EINV  = 163840;   // 16384
constexpr int OFF_M     = 180224;   // 1024
constexpr int OFF_MINV  = 181248;   // 1024
constexpr int OFF_GL2   = 182272;   // 128: (2/lam)*log2e
constexpr int OFF_FH    = 182400;   // 16384  Fh = Einv H31
constexpr int OFF_B1H   = 198784;   // 16384  B1h = Einv H32
constexpr int OFF_B2H   = 215168;   // 4096   B2h = Einv B2
constexpr int OFF_W0    = 219264;   // 4096   W0 = Minv C2
constexpr int OFF_WC    = 223360;   // 4096   WC[k][l] = sum_m W0[k][m] C1[l][m]
constexpr int OFF_CF    = 227456;   // 16384  CF = C1 Fh
constexpr int OFF_CB    = 243840;   // 16384  CB = C1 B1h
constexpr int OFF_CB2   = 260224;   // 4096   CB2 = C1 B2h
constexpr int OFF_PF    = 264320;   // 16384 (8192 f2) PF[j][l]=(Fh[l][j],Fh[l+64][j])
constexpr int OFF_PB    = 280704;   // 16384 B1h pairs
constexpr int OFF_PCF   = 297088;   // 16384 gl2-scaled CF pairs
constexpr int OFF_PCB   = 313472;   // 16384 gl2-scaled CB pairs
constexpr int OFF_SAB   = 329856;   // 8192  (4096 f2) scan couplings lower
constexpr int OFF_SB2   = 338048;   // 4096            scan couplings upper
constexpr int OFF_BUQ   = 342144;   // 4096 (2048 f2) (B2h[l][k],B2h[l+64][k])
constexpr int OFF_D12Q  = 346240;   // 4096 gl2-scaled D12 pairs
constexpr int OFF_SCB2  = 350336;   // 4096 gl2-scaled CB2 pairs
constexpr int OFF_WCS   = 354432;   // 4096 gl2-scaled WC pairs
constexpr int OFF_C2Y   = 358528;   // 4096  C2Y[m][o] = C2[o][m]
constexpr int OFF_D21Y  = 362624;   // 4096
constexpr int OFF_D22Y  = 366720;   // 1024
constexpr int OFF_AUG   = 367744;   // 32768 (global GJ fallback scratch)
constexpr int OFF_AUG2  = 400512;   // 2048
constexpr int OFF_X0    = 402560;   // 32768
constexpr int OFF_A0    = 435328;   // 32768
constexpr int WS_FLOATS = 468096;

__device__ __align__(16) float g_ws[WS_FLOATS];
__device__ int g_isf32;
__device__ float4 g_Q [256 * 1024 * 64];
__device__ float2 g_Xs[256 * 1024 * 64];
__device__ float2 g_Ws[256 * 1024 * 64];

DEV float ld(const void* p, int i, int f) {
  return f ? ((const float*)p)[i]
           : __bfloat162float(((const __hip_bfloat16*)p)[i]);
}
DEV float rdlane(float v, int l) {
  return __int_as_float(__builtin_amdgcn_readlane(__float_as_int(v), l));
}

// ---------------- Prep 0: detect input dtype ----------------
__global__ void k_detect(const void* __restrict__ X) {
  if (threadIdx.x == 0) {
    const __hip_bfloat16* p = (const __hip_bfloat16*)X;
    int bad = 0;
    for (int i = 0; i < 512; ++i) {
      float v = __bfloat162float(p[i]);
      if (!(v > -1e6f && v < 1e6f)) bad++;
    }
    g_isf32 = (bad > 0) ? 1 : 0;
  }
}

// ---------------- Prep 1: H = X^T X + eps I ----------------
__global__ void k_H(const void* __restrict__ X) {
  const int f = g_isf32;
  float* ws = g_ws;
  int id = blockIdx.x * 256 + threadIdx.x;   // 147456
  int r = id / 384, c = id % 384;
  float acc = 0.f;
  for (int k = 0; k < 384; ++k)
    acc = fmaf(ld(X, k * 384 + r, f), ld(X, k * 384 + c, f), acc);
  if (r == c) acc += 0.001f;
  ws[OFF_H + id] = acc;
}

// ---------------- Prep 2: E, gl2, M ----------------
__global__ void k_derived(const void* __restrict__ Y, const void* __restrict__ C2) {
  const int f = g_isf32;
  float* ws = g_ws;
  const float* H = ws + OFF_H;
  int id = blockIdx.x * 256 + threadIdx.x;
  if (id < 16384) {
    int i = id >> 7, j = id & 127;
    ws[OFF_E + id] = 0.5f * (H[i * 384 + j] + H[(256 + i) * 384 + 256 + j]
                             + ld(Y, i * 128 + j, f) - ld(Y, j * 128 + i, f));
  } else if (id < 16512) {
    int i = id - 16384;
    ws[OFF_GL2 + i] = LOG2E * 4.f / H[(128 + i) * 384 + 128 + i];
  } else if (id < 17536) {
    int t = id - 16512; int a = t >> 5, b = t & 31;
    float acc = 0.f;
    for (int j = 0; j < 128; ++j)
      acc = fmaf(ld(C2, a * 128 + j, f), ld(C2, b * 128 + j, f), acc);
    ws[OFF_M + t] = acc;
  }
}

// ---------------- Prep 3: invert E (128) and M (32) — LDS-resident GJ ----------------
__global__ void k_inv_lds() {
  extern __shared__ float smv[];
  float* aug  = smv;            // 128x256
  float* aug2 = smv + 32768;    // 32x64
  __shared__ float col[128];
  float* ws = g_ws;
  const float* E = ws + OFF_E;
  int tid = threadIdx.x;
  for (int idx = tid; idx < 32768; idx += 1024) {
    int i = idx >> 8, j = idx & 255;
    aug[idx] = (j < 128) ? E[i * 128 + j] : ((j - 128) == i ? 1.f : 0.f);
  }
  __syncthreads();
  for (int k = 0; k < 128; ++k) {
    if (tid < 128) col[tid] = aug[tid * 256 + k];
    __syncthreads();
    float d = 1.f / col[k];
    if (tid < 256) aug[k * 256 + tid] *= d;
    __syncthreads();
    int j = tid & 255, iseg = tid >> 8;
    float rkj = aug[k * 256 + j];
    for (int i = iseg * 32; i < iseg * 32 + 32; ++i) {
      if (i == k) continue;
      aug[i * 256 + j] -= col[i] * rkj;
    }
    __syncthreads();
  }
  for (int idx = tid; idx < 16384; idx += 1024) {
    int i = idx >> 7, j = idx & 127;
    ws[OFF_EINV + idx] = aug[i * 256 + 128 + j];
  }
  const float* M = ws + OFF_M;
  for (int idx = tid; idx < 2048; idx += 1024) {
    int i = idx >> 6, j = idx & 63;
    aug2[idx] = (j < 32) ? M[i * 32 + j] : ((j - 32) == i ? 1.f : 0.f);
  }
  __syncthreads();
  for (int k = 0; k < 32; ++k) {
    if (tid < 32) col[tid] = aug2[tid * 64 + k];
    __syncthreads();
    float d = 1.f / col[k];
    if (tid < 64) aug2[k * 64 + tid] *= d;
    __syncthreads();
    if (tid < 64) {
      float rkj = aug2[k * 64 + tid];
      for (int i = 0; i < 32; ++i) if (i != k) aug2[i * 64 + tid] -= col[i] * rkj;
    }
    __syncthreads();
  }
  for (int idx = tid; idx < 1024; idx += 1024) {
    int i = idx >> 5, j = idx & 31;
    ws[OFF_MINV + idx] = aug2[i * 64 + 32 + j];
  }
}

// Fallback: global-scratch GJ (round-6 verified)
__global__ void k_inv() {
  float* ws = g_ws;
  __shared__ float col[128];
  float* aug = ws + OFF_AUG;
  const float* E = ws + OFF_E;
  int tid = threadIdx.x;
  for (int idx = tid; idx < 32768; idx += 1024) {
    int i = idx >> 8, j = idx & 255;
    aug[idx] = (j < 128) ? E[i * 128 + j] : ((j - 128) == i ? 1.f : 0.f);
  }
  __syncthreads();
  for (int k = 0; k < 128; ++k) {
    if (tid < 128) col[tid] = aug[tid * 256 + k];
    __syncthreads();
    float d = 1.f / col[k];
    if (tid < 256) aug[k * 256 + tid] *= d;
    __syncthreads();
    int j = tid & 255, iseg = tid >> 8;
    float rkj = aug[k * 256 + j];
    for (int i = iseg * 32; i < iseg * 32 + 32; ++i) {
      if (i == k) continue;
      aug[i * 256 + j] -= col[i] * rkj;
    }
    __syncthreads();
  }
  for (int idx = tid; idx < 16384; idx += 1024) {
    int i = idx >> 7, j = idx & 127;
    ws[OFF_EINV + idx] = aug[i * 256 + 128 + j];
  }
  __syncthreads();
  float* aug2 = ws + OFF_AUG2;
  const float* M = ws + OFF_M;
  for (int idx = tid; idx < 2048; idx += 1024) {
    int i = idx >> 6, j = idx & 63;
    aug2[idx] = (j < 32) ? M[i * 32 + j] : ((j - 32) == i ? 1.f : 0.f);
  }
  __syncthreads();
  for (int k = 0; k < 32; ++k) {
    if (tid < 32) col[tid] = aug2[tid * 64 + k];
    __syncthreads();
    float d = 1.f / col[k];
    if (tid < 64) aug2[k * 64 + tid] *= d;
    __syncthreads();
    if (tid < 64) {
      float rkj = aug2[k * 64 + tid];
      for (int i = 0; i < 32; ++i) if (i != k) aug2[i * 64 + tid] -= col[i] * rkj;
    }
    __syncthreads();
  }
  for (int idx = tid; idx < 1024; idx += 1024) {
    int i = idx >> 5, j = idx & 31;
    ws[OFF_MINV + idx] = aug2[i * 64 + 32 + j];
  }
}

// ---------------- Prep 4: Fh, B1h, B2h, W0 ----------------
__global__ void k_fuse(const void* __restrict__ B2, const void* __restrict__ C2) {
  const int f = g_isf32;
  float* ws = g_ws;
  const float* einv = ws + OFF_EINV;
  const float* H = ws + OFF_H;
  const float* minv = ws + OFF_MINV;
  int id = blockIdx.x * 256 + threadIdx.x;   // 40960
  if (id < 16384) {
    int l = id >> 7, j = id & 127;
    float a = 0.f;
    for (int m = 0; m < 128; ++m) a = fmaf(einv[l * 128 + m], H[(256 + m) * 384 + j], a);
    ws[OFF_FH + id] = a;
  } else if (id < 32768) {
    int t = id - 16384; int l = t >> 7, j = t & 127;
    float a = 0.f;
    for (int m = 0; m < 128; ++m) a = fmaf(einv[l * 128 + m], H[(256 + m) * 384 + 128 + j], a);
    ws[OFF_B1H + t] = a;
  } else if (id < 36864) {
    int t = id - 32768; int l = t >> 5, k = t & 31;
    float a = 0.f;
    for (int m = 0; m < 128; ++m) a = fmaf(einv[l * 128 + m], ld(B2, m * 32 + k, f), a);
    ws[OFF_B2H + t] = a;
  } else if (id < 40960) {
    int t = id - 36864; int k = t >> 7, l = t & 127;
    float a = 0.f;
    for (int m = 0; m < 32; ++m) a = fmaf(minv[k * 32 + m], ld(C2, m * 128 + l, f), a);
    ws[OFF_W0 + t] = a;
  }
}

// ---------------- Prep 5: WC ----------------
__global__ void k_w2() {
  float* ws = g_ws;
  const float* H = ws + OFF_H;
  const float* w0 = ws + OFF_W0;
  int id = blockIdx.x * 256 + threadIdx.x;   // 4096
  int k = id >> 7, l = id & 127;
  float a = 0.f;
  for (int m = 0; m < 128; ++m) a = fmaf(w0[k * 128 + m], -H[(128 + l) * 384 + m], a);
  ws[OFF_WC + id] = a;
}

// ---------------- Prep 6: CF = C1 Fh, CB = C1 B1h, CB2 = C1 B2h ----------------
__global__ void k_cf() {
  float* ws = g_ws;
  const float* H = ws + OFF_H;
  int id = blockIdx.x * 256 + threadIdx.x;   // 36864
  if (id < 16384) {
    int l = id >> 7, j = id & 127;
    float a = 0.f;
    for (int m = 0; m < 128; ++m) a = fmaf(-H[(128 + l) * 384 + m], ws[OFF_FH + m * 128 + j], a);
    ws[OFF_CF + id] = a;
  } else if (id < 32768) {
    int t = id - 16384; int l = t >> 7, j = t & 127;
    float a = 0.f;
    for (int m = 0; m < 128; ++m) a = fmaf(-H[(128 + l) * 384 + m], ws[OFF_B1H + m * 128 + j], a);
    ws[OFF_CB + t] = a;
  } else {
    int t = id - 32768; int l = t >> 5, k = t & 31;
    float a = 0.f;
    for (int m = 0; m < 128; ++m) a = fmaf(-H[(128 + l) * 384 + m], ws[OFF_B2H + m * 32 + k], a);
    ws[OFF_CB2 + t] = a;
  }
}

// ---------------- Prep 7: packed/scaled layouts ----------------
__global__ void k_pk(const void* __restrict__ D12, const void* __restrict__ C2,
                     const void* __restrict__ D21, const void* __restrict__ D22) {
  const int f = g_isf32;
  float* ws = g_ws;
  const float* H = ws + OFF_H;
  const float* g = ws + OFF_GL2;
  int id = blockIdx.x * 256 + threadIdx.x;   // 58368
  if (id < 8192) {                   // PF
    int j = id >> 6, l = id & 63;
    ((float2*)(ws + OFF_PF))[id] =
        make_float2(ws[OFF_FH + l * 128 + j], ws[OFF_FH + (l + 64) * 128 + j]);
  } else if (id < 16384) {           // PB
    int t = id - 8192; int j = t >> 6, l = t & 63;
    ((float2*)(ws + OFF_PB))[t] =
        make_float2(ws[OFF_B1H + l * 128 + j], ws[OFF_B1H + (l + 64) * 128 + j]);
  } else if (id < 24576) {           // PCF (gl2-scaled rows)
    int t = id - 16384; int j = t >> 6, l = t & 63;
    ((float2*)(ws + OFF_PCF))[t] =
        make_float2(g[l] * ws[OFF_CF + l * 128 + j], g[l + 64] * ws[OFF_CF + (l + 64) * 128 + j]);
  } else if (id < 32768) {           // PCB
    int t = id - 24576; int j = t >> 6, l = t & 63;
    ((float2*)(ws + OFF_PCB))[t] =
        make_float2(g[l] * ws[OFF_CB + l * 128 + j], g[l + 64] * ws[OFF_CB + (l + 64) * 128 + j]);
  } else if (id < 36864) {           // SAB
    int t = id - 32768; int i = t >> 6, l = t & 63;
    float sx = (i < l) ? -g[l] * H[(128 + l) * 384 + 128 + i] : 0.f;
    float sy = -g[l + 64] * H[(192 + l) * 384 + 128 + i];
    ((float2*)(ws + OFF_SAB))[t] = make_float2(sx, sy);
  } else if (id < 40960) {           // SB2
    int t = id - 36864; int ii = t >> 6, l = t & 63;
    ws[OFF_SB2 + t] = (ii < l) ? -g[l + 64] * H[(192 + l) * 384 + 192 + ii] : 0.f;
  } else if (id < 43008) {           // BUQ
    int t = id - 40960; int k = t >> 6, l = t & 63;
    ((float2*)(ws + OFF_BUQ))[t] =
        make_float2(ws[OFF_B2H + l * 32 + k], ws[OFF_B2H + (l + 64) * 32 + k]);
  } else if (id < 45056) {           // D12Q
    int t = id - 43008; int k = t >> 6, l = t & 63;
    ((float2*)(ws + OFF_D12Q))[t] =
        make_float2(g[l] * ld(D12, l * 32 + k, f), g[l + 64] * ld(D12, (l + 64) * 32 + k, f));
  } else if (id < 47104) {           // SCB2
    int t = id - 45056; int k = t >> 6, l = t & 63;
    ((float2*)(ws + OFF_SCB2))[t] =
        make_float2(g[l] * ws[OFF_CB2 + l * 32 + k], g[l + 64] * ws[OFF_CB2 + (l + 64) * 32 + k]);
  } else if (id < 49152) {           // WCS
    int t = id - 47104; int k = t >> 6, l = t & 63;
    ((float2*)(ws + OFF_WCS))[t] =
        make_float2(g[l] * ws[OFF_WC + k * 128 + l], g[l + 64] * ws[OFF_WC + k * 128 + l + 64]);
  } else if (id < 53248) {           // C2Y
    int t = id - 49152; int m = t >> 5, o = t & 31;
    ws[OFF_C2Y + t] = ld(C2, o * 128 + m, f);
  } else if (id < 57344) {           // D21Y
    int t = id - 53248; int m = t >> 5, o = t & 31;
    ws[OFF_D21Y + t] = ld(D21, o * 128 + m, f);
  } else if (id < 58368) {           // D22Y
    int t = id - 57344; int k = t >> 5, o = t & 31;
    ws[OFF_D22Y + t] = ld(D22, o * 32 + k, f);
  }
}

// ---------------- Prep 8: x0 and a0 ----------------
__global__ void k_x0a0(const void* __restrict__ x0s, const void* __restrict__ u_in) {
  const int f = g_isf32;
  float* ws = g_ws;
  int id = blockIdx.x * 256 + threadIdx.x;   // 49152
  if (id < 32768) {
    int b = id >> 7, l = id & 127;
    float a = 0.f;
    for (int k = 0; k < 32; ++k)
      a = fmaf(ld(x0s, b * 32 + k, f), ws[OFF_W0 + k * 128 + l], a);
    ws[OFF_X0 + id] = a;
  } else {
    int t = id - 32768; int b = t >> 6, lane = t & 63;
    const float2* WCs = (const float2*)(ws + OFF_WCS);
    const float2* D12Q = (const float2*)(ws + OFF_D12Q);
    float ax = 0.f, ay = 0.f;
    for (int k = 0; k < 32; ++k) {
      float yk = ld(x0s, b * 32 + k, f);
      float2 wc = WCs[k * 64 + lane];
      ax = fmaf(wc.x, yk, ax); ay = fmaf(wc.y, yk, ay);
      float u0 = ld(u_in, b * Tn * 32 + k, f);
      float2 dq = D12Q[k * 64 + lane];
      ax = fmaf(dq.x, u0, ax); ay = fmaf(dq.y, u0, ay);
    }
    ((float2*)(ws + OFF_A0))[b * 64 + lane] = make_float2(ax, ay);
  }
}

// ---------------- Prep 9: u-injection stream (bu for x', qa for a') ----------------
__global__ __launch_bounds__(256) void k_q(const void* __restrict__ u_in) {
  const int f = g_isf32;
  const float* ws = g_ws;
  int lane = threadIdx.x & 63, wave = threadIdx.x >> 6;
  int idx = blockIdx.x * 4 + wave;
  int b = idx >> 10, t = idx & 1023;
  if (t >= Tn - 1) return;
  const float2* BUq = (const float2*)(ws + OFF_BUQ);
  const float2* SCB2 = (const float2*)(ws + OFF_SCB2);
  const float2* D12Q = (const float2*)(ws + OFF_D12Q);
  float bx = 0.f, by = 0.f, ax = 0.f, ay = 0.f;
#pragma unroll 8
  for (int k = 0; k < 32; ++k) {
    float u0 = ld(u_in, (b * Tn + t) * 32 + k, f);
    float2 bu = BUq[k * 64 + lane];
    bx = fmaf(bu.x, u0, bx); by = fmaf(bu.y, u0, by);
    float2 sc = SCB2[k * 64 + lane];
    ax = fmaf(sc.x, u0, ax); ay = fmaf(sc.y, u0, ay);
    float u1 = ld(u_in, (b * Tn + t + 1) * 32 + k, f);
    float2 dq = D12Q[k * 64 + lane];
    ax = fmaf(dq.x, u1, ax); ay = fmaf(dq.y, u1, ay);
  }
  g_Q[((size_t)b * Tn + t) * 64 + lane] = make_float4(bx, by, ax, ay);
}

// ---------------- Main: 1 row/block, 8 waves, ONE barrier/step ----------------
__global__ __launch_bounds__(512) void k_scan8() {
  __shared__ float2 sSAB[64 * 64];     // 32 KB
  __shared__ float  sSB2[64 * 64];     // 16 KB
  __shared__ float2 xbuf[2][8][64];    // 8 KB (parity double-buffered)
  __shared__ float2 abuf[2][8][64];    // 8 KB
  const float* ws = g_ws;
  const int tid = threadIdx.x, lane = tid & 63, w = tid >> 6;
  for (int i = tid; i < 4096; i += 512) sSAB[i] = ((const float2*)(ws + OFF_SAB))[i];
  for (int i = tid; i < 4096; i += 512) sSB2[i] = ws[OFF_SB2 + i];

  // 16 columns per wave for each of Fh, B1h, CF, CB (gl2-scaled on CF/CB)
  float2 vFh[16], vB1[16], vCF[16], vCB[16];
  {
    const float2* PF = (const float2*)(ws + OFF_PF);
    const float2* PB = (const float2*)(ws + OFF_PB);
    const float2* PCF = (const float2*)(ws + OFF_PCF);
    const float2* PCB = (const float2*)(ws + OFF_PCB);
#pragma unroll
    for (int c = 0; c < 16; ++c) {
      int j = 16 * w + c;
      vFh[c] = PF[j * 64 + lane];
      vB1[c] = PB[j * 64 + lane];
      vCF[c] = PCF[j * 64 + lane];
      vCB[c] = PCB[j * 64 + lane];
    }
  }
  const int b = blockIdx.x;
  float xl = ws[OFF_X0 + b * 128 + lane];
  float xh = ws[OFF_X0 + b * 128 + 64 + lane];
  float2 a2 = ((const float2*)(ws + OFF_A0))[b * 64 + lane];
  float accx = a2.x, accy = a2.y;
  const float4* Q = g_Q + (size_t)b * Tn * 64;
  float4 q = Q[lane];
  size_t sbase = (size_t)b * Tn * 64 + lane;
  // wave-uniform column base in an SGPR
  const int jo = __builtin_amdgcn_readfirstlane((w < 4) ? 16 * w : 16 * w - 64);
  const bool lowhalf = (w < 4);
  __syncthreads();

#pragma unroll 1
  for (int t = 0; t < Tn - 1; ++t) {
    float4 qn = q;
    if (t + 1 < Tn - 1) qn = Q[(size_t)(t + 1) * 64 + lane];

    // --- serial tanh scan (no in-chain capture; D11 strictly lower) ---
#pragma unroll
    for (int i = 0; i < 64; ++i) {
      float s = rdlane(accx, i);
      float e2 = __builtin_amdgcn_exp2f(s);
      float wi = fmaf(-2.f, __builtin_amdgcn_rcpf(1.f + e2), 1.f);
      float2 sp = sSAB[i * 64 + lane];
      accx = fmaf(sp.x, wi, accx);
      accy = fmaf(sp.y, wi, accy);
    }
    float ex = __builtin_amdgcn_exp2f(accx);               // accx now final
    float wx = fmaf(-2.f, __builtin_amdgcn_rcpf(1.f + ex), 1.f);
#pragma unroll
    for (int i = 0; i < 64; ++i) {
      float s = rdlane(accy, i);
      float e2 = __builtin_amdgcn_exp2f(s);
      float wi = fmaf(-2.f, __builtin_amdgcn_rcpf(1.f + e2), 1.f);
      accy = fmaf(sSB2[i * 64 + lane], wi, accy);
    }
    float ey = __builtin_amdgcn_exp2f(accy);               // accy now final
    float wy = fmaf(-2.f, __builtin_amdgcn_rcpf(1.f + ey), 1.f);
    if (w == 0) g_Ws[sbase + (size_t)t * 64] = make_float2(wx, wy);

    // --- fused x' and a' partials over this wave's 16 columns ---
    float px, py, pax, pay;
    if (w == 0) { px = q.x; py = q.y; pax = q.z; pay = q.w; }
    else        { px = 0.f; py = 0.f; pax = 0.f; pay = 0.f; }
    float xsrc = lowhalf ? xl : xh;
    float wsrc = lowhalf ? wx : wy;
#pragma unroll
    for (int c = 0; c < 16; ++c) {
      float xj = rdlane(xsrc, jo + c);
      float wj = rdlane(wsrc, jo + c);
      px  = fmaf(vFh[c].x, xj, px);
      py  = fmaf(vFh[c].y, xj, py);
      px  = fmaf(vB1[c].x, wj, px);
      py  = fmaf(vB1[c].y, wj, py);
      pax = fmaf(vCF[c].x, xj, pax);
      pay = fmaf(vCF[c].y, xj, pay);
      pax = fmaf(vCB[c].x, wj, pax);
      pay = fmaf(vCB[c].y, wj, pay);
    }
    int p = t & 1;
    xbuf[p][w][lane] = make_float2(px, py);
    abuf[p][w][lane] = make_float2(pax, pay);
    __syncthreads();                                       // the ONLY barrier

    float sxl = 0.f, sxh = 0.f, sax = 0.f, say = 0.f;
#pragma unroll
    for (int w2 = 0; w2 < 8; ++w2) {
      float2 xv = xbuf[p][w2][lane];
      float2 av = abuf[p][w2][lane];
      sxl += xv.x; sxh += xv.y;
      sax += av.x; say += av.y;
    }
    xl = sxl; xh = sxh; accx = sax; accy = say;
    if (w == 1) g_Xs[sbase + (size_t)(t + 1) * 64] = make_float2(xl, xh);
    q = qn;
  }
}

// ---------------- Output GEMM ----------------
__global__ __launch_bounds__(256) void k_y(const void* __restrict__ x0s,
                                           const void* __restrict__ u_in,
                                           void* __restrict__ out) {
  const int f = g_isf32;
  const float* ws = g_ws;
  int lane = threadIdx.x & 63, wave = threadIdx.x >> 6;
  int idx = blockIdx.x * 4 + wave;
  int b = idx >> 10, tau = idx & 1023;
  int o = lane & 31, h = lane >> 5;
  if (tau == 0) {
    if (lane < 32) {
      size_t oi = (size_t)b * Tn * 32 + o;
      float v = ld(x0s, b * 32 + o, f);
      if (f) ((float*)out)[oi] = v;
      else   ((__hip_bfloat16*)out)[oi] = __float2bfloat16(v);
    }
    return;
  }
  const float* Xf = (const float*)g_Xs;
  const float* Wf = (const float*)g_Ws;
  const float* C2Y = ws + OFF_C2Y;
  const float* D21Y = ws + OFF_D21Y;
  const float* D22Y = ws + OFF_D22Y;
  size_t rbase = ((size_t)b * Tn + tau) * 128;
  size_t pbase = ((size_t)b * Tn + tau - 1) * 128;
  float acc = 0.f;
#pragma unroll 8
  for (int l = 0; l < 64; ++l)
    acc = fmaf(Xf[rbase + 2 * l + h], C2Y[(l + 64 * h) * 32 + o], acc);
#pragma unroll 8
  for (int l = 0; l < 64; ++l)
    acc = fmaf(Wf[pbase + 2 * l + h], D21Y[(l + 64 * h) * 32 + o], acc);
  if (h == 0) {
#pragma unroll 8
    for (int k = 0; k < 32; ++k)
      acc = fmaf(ld(u_in, (b * Tn + tau - 1) * 32 + k, f), D22Y[k * 32 + o], acc);
  }
  acc += __shfl_down(acc, 32);
  if (lane < 32) {
    size_t oi = ((size_t)b * Tn + tau) * 32 + o;
    if (f) ((float*)out)[oi] = acc;
    else   ((__hip_bfloat16*)out)[oi] = __float2bfloat16(acc);
  }
}

extern "C" void kernel_launch(void* const* d_in, const int* in_sizes, int n_in,
                              void* d_out, int out_size, void* d_ws, size_t ws_size,
                              hipStream_t stream) {
  const void* x0s = d_in[0];
  const void* u   = d_in[1];
  const void* X   = d_in[2];
  const void* Y   = d_in[3];
  const void* B2  = d_in[4];
  const void* C2  = d_in[5];
  const void* D21 = d_in[6];
  const void* D22 = d_in[7];
  const void* D12 = d_in[8];
  (void)d_ws; (void)ws_size; (void)in_sizes; (void)n_in; (void)out_size;

  hipLaunchKernelGGL(k_detect,  dim3(1),     dim3(64),   0, stream, X);
  hipLaunchKernelGGL(k_H,       dim3(576),   dim3(256),  0, stream, X);
  hipLaunchKernelGGL(k_derived, dim3(69),    dim3(256),  0, stream, Y, C2);

  hipError_t e = hipFuncSetAttribute((const void*)k_inv_lds,
                                     hipFuncAttributeMaxDynamicSharedMemorySize,
                                     139264);
  if (e == hipSuccess) {
    hipLaunchKernelGGL(k_inv_lds, dim3(1), dim3(1024), 139264, stream);
  } else {
    (void)hipGetLastError();
    hipLaunchKernelGGL(k_inv,     dim3(1), dim3(1024), 0, stream);
  }

  hipLaunchKernelGGL(k_fuse,    dim3(160),   dim3(256),  0, stream, B2, C2);
  hipLaunchKernelGGL(k_w2,      dim3(16),    dim3(256),  0, stream);
  hipLaunchKernelGGL(k_cf,      dim3(144),   dim3(256),  0, stream);
  hipLaunchKernelGGL(k_pk,      dim3(228),   dim3(256),  0, stream, D12, C2, D21, D22);
  hipLaunchKernelGGL(k_x0a0,    dim3(192),   dim3(256),  0, stream, x0s, u);
  hipLaunchKernelGGL(k_q,       dim3(65536), dim3(256),  0, stream, u);
  hipLaunchKernelGGL(k_scan8,   dim3(256),   dim3(512),  0, stream);
  hipLaunchKernelGGL(k_y,       dim3(65536), dim3(256),  0, stream, x0s, u, d_out);
}